// Round 3
// baseline (838.024 us; speedup 1.0000x reference)
//
#include <hip/hip_runtime.h>
#include <hip/hip_bf16.h>

#define N_NODES 100000
#define N_EDGES 1600000
#define D 64
#define WSCALE 32767.0f

#define BSHIFT 9
#define BNODES 512                                  // nodes per bucket
#define NB 196                                      // ceil(100000/512)
#define CAP_B 8960                                  // mean 8192, sd ~90 -> 8.5 sigma
#define CHUNK 4096
#define NBIN_BLOCKS ((N_EDGES + CHUNK - 1) / CHUNK) // 391

__device__ inline ushort f2bu(float f) {
    __hip_bfloat16 h = __float2bfloat16(f);
    return *(ushort*)&h;
}

// ---------------------------------------------------------------------------
// 1. Bin edges by dst bucket. (byte-identical to prior round — known good)
// ---------------------------------------------------------------------------
__global__ __launch_bounds__(256) void bin_kernel(
    const int* __restrict__ src,
    const int* __restrict__ dst,
    const float* __restrict__ w,
    int* __restrict__ gcur,
    int2* __restrict__ bucketed)
{
    __shared__ int h[NB];
    __shared__ int cur[NB];
    __shared__ int sdst[CHUNK];      // 16 KB
    int tid = threadIdx.x;
    for (int b = tid; b < NB; b += 256) h[b] = 0;
    __syncthreads();

    int e0 = blockIdx.x * CHUNK;
    for (int i = tid; i < CHUNK; i += 256) {
        int e = e0 + i;
        int d = (e < N_EDGES) ? dst[e] : -1;
        sdst[i] = d;
        if (d >= 0) atomicAdd(&h[d >> BSHIFT], 1);
    }
    __syncthreads();

    for (int b = tid; b < NB; b += 256) {
        int c = h[b];
        cur[b] = (c > 0) ? atomicAdd(&gcur[b], c) : 0;
    }
    __syncthreads();

    for (int i = tid; i < CHUNK; i += 256) {
        int e = e0 + i;
        int d = sdst[i];
        if (d >= 0) {
            int b = d >> BSHIFT;
            int p = atomicAdd(&cur[b], 1);
            int q = (int)(w[e] * WSCALE + 0.5f);
            q = min(q, 32767);
            unsigned pk = (unsigned)src[e] | ((unsigned)q << 17);
            if (p < CAP_B)
                bucketed[(size_t)b * CAP_B + p] = make_int2((int)pk, d & (BNODES - 1));
        }
    }
}

// ---------------------------------------------------------------------------
// 2a. Convert x -> bf16 (xb). (unchanged)
// ---------------------------------------------------------------------------
__global__ __launch_bounds__(256) void convert_kernel(
    const float* __restrict__ x,
    ushort* __restrict__ xb)
{
    int i = (blockIdx.x * 256 + threadIdx.x) * 4;
    if (i >= N_NODES * D) return;
    float4 v = *(const float4*)(x + i);
    ushort4 o;
    o.x = f2bu(v.x); o.y = f2bu(v.y); o.z = f2bu(v.z); o.w = f2bu(v.w);
    *(ushort4*)(xb + i) = o;
}

// ---------------------------------------------------------------------------
// 2b. Convert Wrel|Wroot -> bf16 once. (unchanged)
// ---------------------------------------------------------------------------
__global__ __launch_bounds__(256) void wprep_kernel(
    const float* __restrict__ Wrel,
    const float* __restrict__ Wroot,
    ushort* __restrict__ wb)
{
    int i = blockIdx.x * 256 + threadIdx.x;   // 0..8191
    if (i >= 2 * D * D) return;
    float f = (i < D * D) ? Wrel[i] : Wroot[i - D * D];
    wb[i] = f2bu(f);
}

// ---------------------------------------------------------------------------
// 3. Fused scatter-aggregate: replaces bucket_fill + gather. One block per
//    bucket; the whole bucket's agg tile (512 nodes x 64 feats x fp32 =
//    128 KiB) lives in LDS. Each WAVE processes one edge per step: lane f
//    loads xb[src*64+f] (one coalesced 128 B line) and ds_add_f32's into
//    acc[dl*64+f] — bank = f mod 32, exactly 2 lanes/bank = conflict-free.
//    16 edges are batched per wave iteration so ~16 meta + 16 feature
//    loads stay in flight (8 waves -> ~128 outstanding/CU) to hide random
//    L2/L3 latency. Epilogue converts the tile to bf16 and stores aggb.
// ---------------------------------------------------------------------------
#define EB 16   // edges per wave batch

__global__ __launch_bounds__(512) void scatter_kernel(
    const int* __restrict__ gcur,
    const int2* __restrict__ bucketed,
    const ushort* __restrict__ xb,
    ushort* __restrict__ aggb)
{
    __shared__ float acc[BNODES * D];   // 128 KiB (gfx950 LDS: 160 KiB/CU)

    int tid  = threadIdx.x;
    int b    = blockIdx.x;
    int wv   = tid >> 6, lane = tid & 63;

    // zero the tile: 512 threads x 16 x float4 = 128 KiB
#pragma unroll
    for (int i = 0; i < (BNODES * D) / (512 * 4); ++i)
        *(float4*)&acc[(i * 512 + tid) * 4] = make_float4(0.f, 0.f, 0.f, 0.f);
    __syncthreads();

    int nE = min(gcur[b], CAP_B);
    const int2* __restrict__ be = bucketed + (size_t)b * CAP_B;

    for (int j0 = wv * EB; j0 < nE; j0 += 8 * EB) {
        int   dl[EB];
        float ww[EB];
        ushort hx[EB];
        int nv = nE - j0;                       // wave-uniform
#pragma unroll
        for (int u = 0; u < EB; ++u) {
            if (u < nv) {
                int2 mm = be[j0 + u];           // same addr all lanes: broadcast
                unsigned v = (unsigned)mm.x;
                ww[u] = (float)(v >> 17) * (1.0f / WSCALE);
                dl[u] = mm.y;
                hx[u] = xb[(size_t)(v & 0x1FFFF) * D + lane];
            } else dl[u] = -1;
        }
#pragma unroll
        for (int u = 0; u < EB; ++u)
            if (dl[u] >= 0)
                atomicAdd(&acc[dl[u] * D + lane],
                          __uint_as_float((unsigned)hx[u] << 16) * ww[u]);
    }
    __syncthreads();

    // writeout: bf16, coalesced uint stores (2 feats/thread/iter)
    int base = b * BNODES;
    for (int i = tid; i < (BNODES * D) / 2; i += 512) {
        int j = i * 2;
        int n = j >> 6;                 // node-in-bucket
        int node = base + n;
        if (node >= N_NODES) break;     // only trims bucket 195's tail
        int f = j & 63;
        ushort2 o;
        o.x = f2bu(acc[n * D + f]);
        o.y = f2bu(acc[n * D + f + 1]);
        *(ushort2*)(aggb + (size_t)node * D + f) = o;
    }
}

// ---------------------------------------------------------------------------
// 4. Linear via bf16 MFMA (16x16x32). (byte-identical to prior round)
// ---------------------------------------------------------------------------
typedef __attribute__((ext_vector_type(8))) short bf8;
typedef __attribute__((ext_vector_type(4))) float f4;

__global__ __launch_bounds__(256) void linear_kernel(
    const ushort* __restrict__ xb,
    const ushort* __restrict__ aggb,
    float* __restrict__ out,
    const ushort* __restrict__ wb,    // [2][64][64] bf16: Wrel | Wroot
    const float* __restrict__ brel)
{
    __shared__ float __align__(16) sOut[4][16][68];   // 17.4 KB, per-wave use

    int tid  = threadIdx.x;
    int wv   = tid >> 6, lane = tid & 63;
    int node0 = (blockIdx.x * 4 + wv) * 16;
    if (node0 >= N_NODES) return;     // wave-uniform; no barriers below

    int m    = lane & 15;             // node-in-tile (A) / out-col (B, C/D)
    int quad = lane >> 4;             // 0..3

    // ---- B fragments: direct bf16 loads ----
    bf8 bw[2][4][2];                  // [mat][ntile][kstep]
#pragma unroll
    for (int mat = 0; mat < 2; ++mat)
#pragma unroll
        for (int nt = 0; nt < 4; ++nt)
#pragma unroll
            for (int s = 0; s < 2; ++s)
                bw[mat][nt][s] = *(const bf8*)(wb + mat * D * D
                                               + (16 * nt + m) * 64 + s * 32 + quad * 8);

    // ---- A fragments: agg (native bf16) and x (native bf16) ----
    const ushort* ar = aggb + (size_t)(node0 + m) * 64 + quad * 8;
    bf8 aagg0 = *(const bf8*)ar;
    bf8 aagg1 = *(const bf8*)(ar + 32);
    const ushort* xr = xb + (size_t)(node0 + m) * 64 + quad * 8;
    bf8 ax0 = *(const bf8*)xr;
    bf8 ax1 = *(const bf8*)(xr + 32);

    // ---- 16 MFMAs: 4 ntiles x (2 Ksteps x 2 matrices), bias in C-init ----
    f4 acc[4];
#pragma unroll
    for (int nt = 0; nt < 4; ++nt) {
        float b = brel[16 * nt + m];
        f4 c = {b, b, b, b};
        c = __builtin_amdgcn_mfma_f32_16x16x32_bf16(aagg0, bw[0][nt][0], c, 0, 0, 0);
        c = __builtin_amdgcn_mfma_f32_16x16x32_bf16(aagg1, bw[0][nt][1], c, 0, 0, 0);
        c = __builtin_amdgcn_mfma_f32_16x16x32_bf16(ax0,   bw[1][nt][0], c, 0, 0, 0);
        c = __builtin_amdgcn_mfma_f32_16x16x32_bf16(ax1,   bw[1][nt][1], c, 0, 0, 0);
        acc[nt] = c;
    }

    // ---- epilogue: relu, per-wave LDS transpose, coalesced stores ----
#pragma unroll
    for (int nt = 0; nt < 4; ++nt)
#pragma unroll
        for (int r = 0; r < 4; ++r)
            sOut[wv][quad * 4 + r][16 * nt + m] = fmaxf(acc[nt][r], 0.f);
#pragma unroll
    for (int p = 0; p < 4; ++p) {
        int idx = p * 64 + lane;          // 0..255
        int row = idx >> 4;               // 0..15
        int c4  = (idx & 15) * 4;         // 0..60
        float4 v = *(const float4*)&sOut[wv][row][c4];
        *(float4*)(out + (size_t)(node0 + row) * 64 + c4) = v;
    }
}

extern "C" void kernel_launch(void* const* d_in, const int* in_sizes, int n_in,
                              void* d_out, int out_size, void* d_ws, size_t ws_size,
                              hipStream_t stream)
{
    const float* x     = (const float*)d_in[0];
    const int*   eidx  = (const int*)d_in[1];
    const float* eattr = (const float*)d_in[2];
    const float* Wrel  = (const float*)d_in[3];
    const float* brel  = (const float*)d_in[4];
    const float* Wroot = (const float*)d_in[5];
    float* out = (float*)d_out;

    const int* src = eidx;
    const int* dst = eidx + N_EDGES;

    // Workspace (~40 MB of 256 MiB): gcur (pad 1024 ints) | bucketed 14 MB |
    // xb 12.8 MB | wb 16 KB | aggb 12.8 MB. No aliasing: bucketed AND xb
    // are both live during scatter_kernel.
    int*      gcur     = (int*)d_ws;
    int2*     bucketed = (int2*)(gcur + 1024);
    ushort*   xb       = (ushort*)(bucketed + (size_t)NB * CAP_B);
    ushort*   wb       = xb + (size_t)N_NODES * D;
    ushort*   aggb     = wb + 2 * D * D;

    hipMemsetAsync(gcur, 0, NB * sizeof(int), stream);

    bin_kernel<<<NBIN_BLOCKS, 256, 0, stream>>>(src, dst, eattr, gcur, bucketed);
    convert_kernel<<<(N_NODES * D / 4 + 255) / 256, 256, 0, stream>>>(x, xb);
    wprep_kernel<<<(2 * D * D + 255) / 256, 256, 0, stream>>>(Wrel, Wroot, wb);
    scatter_kernel<<<NB, 512, 0, stream>>>(gcur, bucketed, xb, aggb);
    linear_kernel<<<(N_NODES + 63) / 64, 256, 0, stream>>>(xb, aggb, out, wb, brel);
}

// Round 4
// 829.745 us; speedup vs baseline: 1.0100x; 1.0100x over previous
//
#include <hip/hip_runtime.h>
#include <hip/hip_bf16.h>

#define N_NODES 100000
#define N_EDGES 1600000
#define D 64
#define WSCALE 32767.0f

#define BSHIFT 9
#define BNODES 512                                  // nodes per bucket
#define NB 196                                      // ceil(100000/512)
#define CAP_B 8960                                  // mean 8192, sd ~90 -> 8.5 sigma
#define CHUNK 4096
#define NBIN_BLOCKS ((N_EDGES + CHUNK - 1) / CHUNK) // 391

__device__ inline ushort f2bu(float f) {
    __hip_bfloat16 h = __float2bfloat16(f);
    return *(ushort*)&h;
}

// ---------------------------------------------------------------------------
// 1. Bin edges by dst bucket. (byte-identical — known good)
// ---------------------------------------------------------------------------
__global__ __launch_bounds__(256) void bin_kernel(
    const int* __restrict__ src,
    const int* __restrict__ dst,
    const float* __restrict__ w,
    int* __restrict__ gcur,
    int2* __restrict__ bucketed)
{
    __shared__ int h[NB];
    __shared__ int cur[NB];
    __shared__ int sdst[CHUNK];      // 16 KB
    int tid = threadIdx.x;
    for (int b = tid; b < NB; b += 256) h[b] = 0;
    __syncthreads();

    int e0 = blockIdx.x * CHUNK;
    for (int i = tid; i < CHUNK; i += 256) {
        int e = e0 + i;
        int d = (e < N_EDGES) ? dst[e] : -1;
        sdst[i] = d;
        if (d >= 0) atomicAdd(&h[d >> BSHIFT], 1);
    }
    __syncthreads();

    for (int b = tid; b < NB; b += 256) {
        int c = h[b];
        cur[b] = (c > 0) ? atomicAdd(&gcur[b], c) : 0;
    }
    __syncthreads();

    for (int i = tid; i < CHUNK; i += 256) {
        int e = e0 + i;
        int d = sdst[i];
        if (d >= 0) {
            int b = d >> BSHIFT;
            int p = atomicAdd(&cur[b], 1);
            int q = (int)(w[e] * WSCALE + 0.5f);
            q = min(q, 32767);
            unsigned pk = (unsigned)src[e] | ((unsigned)q << 17);
            if (p < CAP_B)
                bucketed[(size_t)b * CAP_B + p] = make_int2((int)pk, d & (BNODES - 1));
        }
    }
}

// ---------------------------------------------------------------------------
// 2a. Convert x -> bf16 (xb). (unchanged)
// ---------------------------------------------------------------------------
__global__ __launch_bounds__(256) void convert_kernel(
    const float* __restrict__ x,
    ushort* __restrict__ xb)
{
    int i = (blockIdx.x * 256 + threadIdx.x) * 4;
    if (i >= N_NODES * D) return;
    float4 v = *(const float4*)(x + i);
    ushort4 o;
    o.x = f2bu(v.x); o.y = f2bu(v.y); o.z = f2bu(v.z); o.w = f2bu(v.w);
    *(ushort4*)(xb + i) = o;
}

// ---------------------------------------------------------------------------
// 2b. Convert Wrel|Wroot -> bf16 once. (unchanged)
// ---------------------------------------------------------------------------
__global__ __launch_bounds__(256) void wprep_kernel(
    const float* __restrict__ Wrel,
    const float* __restrict__ Wroot,
    ushort* __restrict__ wb)
{
    int i = blockIdx.x * 256 + threadIdx.x;   // 0..8191
    if (i >= 2 * D * D) return;
    float f = (i < D * D) ? Wrel[i] : Wroot[i - D * D];
    wb[i] = f2bu(f);
}

// ---------------------------------------------------------------------------
// 3. Fused scatter-aggregate (v2). One block per bucket; the bucket's agg
//    tile (512 x 64 fp32 = 128 KiB) lives in LDS.
//    Round-3 failure: per-u `if` guards put each meta load in its own
//    exec-mask BB, so the scheduler couldn't cluster loads -> each batch
//    cost 16x memory latency (13k cyc/batch, 710 us). Fix:
//      * BRANCHLESS batch body: clamp tail index, zero tail weight, and
//        split into three straight-line unrolled phases (meta loads |
//        feature loads | LDS atomics). All 16 loads of a phase issue
//        back-to-back -> ~2x latency per batch instead of 16x.
//      * 1024-thread blocks: 16 waves/CU (vs 8) for latency hiding.
//    Bank math: acc[dl*64 + lane] -> bank = lane mod 32, 2 lanes/bank =
//    conflict-free (confirmed round 3: SQ_LDS_BANK_CONFLICT = 0).
// ---------------------------------------------------------------------------
#define EB 16   // edges per wave batch

__global__ __launch_bounds__(1024) void scatter_kernel(
    const int* __restrict__ gcur,
    const int2* __restrict__ bucketed,
    const ushort* __restrict__ xb,
    ushort* __restrict__ aggb)
{
    __shared__ float acc[BNODES * D];   // 128 KiB (gfx950 LDS: 160 KiB/CU)

    int tid  = threadIdx.x;
    int b    = blockIdx.x;
    int wv   = tid >> 6, lane = tid & 63;   // wv 0..15

    // zero the tile: 1024 threads x 8 x float4 = 128 KiB
#pragma unroll
    for (int i = 0; i < (BNODES * D) / (1024 * 4); ++i)
        *(float4*)&acc[(i * 1024 + tid) * 4] = make_float4(0.f, 0.f, 0.f, 0.f);
    __syncthreads();

    int nE = min(gcur[b], CAP_B);
    const int2* __restrict__ be = bucketed + (size_t)b * CAP_B;

    for (int j0 = wv * EB; j0 < nE; j0 += 16 * EB) {
        // --- phase 1: meta loads (uniform addr, clamped -> no branches) ---
        unsigned pk[EB];
        int      dl[EB];
#pragma unroll
        for (int u = 0; u < EB; ++u) {
            int idx  = j0 + u;
            int cidx = (idx < nE) ? idx : (nE - 1);   // clamp: always valid
            int2 m   = be[cidx];
            pk[u] = (unsigned)m.x;
            dl[u] = m.y;
        }
        // --- phase 2: feature loads (independent, issue together) ---
        float  ww[EB];
        ushort hx[EB];
#pragma unroll
        for (int u = 0; u < EB; ++u) {
            float w = (float)(pk[u] >> 17) * (1.0f / WSCALE);
            ww[u] = (j0 + u < nE) ? w : 0.0f;         // tail contributes 0
            hx[u] = xb[(size_t)(pk[u] & 0x1FFFF) * D + lane];
        }
        // --- phase 3: LDS atomics (unconditional; +0.0f is a no-op) ---
#pragma unroll
        for (int u = 0; u < EB; ++u)
            atomicAdd(&acc[dl[u] * D + lane],
                      __uint_as_float((unsigned)hx[u] << 16) * ww[u]);
    }
    __syncthreads();

    // writeout: bf16, coalesced (2 feats/thread/iter)
    int base = b * BNODES;
    for (int i = tid; i < (BNODES * D) / 2; i += 1024) {
        int j = i * 2;
        int n = j >> 6;                 // node-in-bucket
        int node = base + n;
        if (node >= N_NODES) break;     // only trims bucket 195's tail
        int f = j & 63;
        ushort2 o;
        o.x = f2bu(acc[n * D + f]);
        o.y = f2bu(acc[n * D + f + 1]);
        *(ushort2*)(aggb + (size_t)node * D + f) = o;
    }
}

// ---------------------------------------------------------------------------
// 4. Linear via bf16 MFMA (16x16x32). (byte-identical — known good)
// ---------------------------------------------------------------------------
typedef __attribute__((ext_vector_type(8))) short bf8;
typedef __attribute__((ext_vector_type(4))) float f4;

__global__ __launch_bounds__(256) void linear_kernel(
    const ushort* __restrict__ xb,
    const ushort* __restrict__ aggb,
    float* __restrict__ out,
    const ushort* __restrict__ wb,    // [2][64][64] bf16: Wrel | Wroot
    const float* __restrict__ brel)
{
    __shared__ float __align__(16) sOut[4][16][68];   // 17.4 KB, per-wave use

    int tid  = threadIdx.x;
    int wv   = tid >> 6, lane = tid & 63;
    int node0 = (blockIdx.x * 4 + wv) * 16;
    if (node0 >= N_NODES) return;     // wave-uniform; no barriers below

    int m    = lane & 15;             // node-in-tile (A) / out-col (B, C/D)
    int quad = lane >> 4;             // 0..3

    // ---- B fragments: direct bf16 loads ----
    bf8 bw[2][4][2];                  // [mat][ntile][kstep]
#pragma unroll
    for (int mat = 0; mat < 2; ++mat)
#pragma unroll
        for (int nt = 0; nt < 4; ++nt)
#pragma unroll
            for (int s = 0; s < 2; ++s)
                bw[mat][nt][s] = *(const bf8*)(wb + mat * D * D
                                               + (16 * nt + m) * 64 + s * 32 + quad * 8);

    // ---- A fragments: agg (native bf16) and x (native bf16) ----
    const ushort* ar = aggb + (size_t)(node0 + m) * 64 + quad * 8;
    bf8 aagg0 = *(const bf8*)ar;
    bf8 aagg1 = *(const bf8*)(ar + 32);
    const ushort* xr = xb + (size_t)(node0 + m) * 64 + quad * 8;
    bf8 ax0 = *(const bf8*)xr;
    bf8 ax1 = *(const bf8*)(xr + 32);

    // ---- 16 MFMAs: 4 ntiles x (2 Ksteps x 2 matrices), bias in C-init ----
    f4 acc[4];
#pragma unroll
    for (int nt = 0; nt < 4; ++nt) {
        float b = brel[16 * nt + m];
        f4 c = {b, b, b, b};
        c = __builtin_amdgcn_mfma_f32_16x16x32_bf16(aagg0, bw[0][nt][0], c, 0, 0, 0);
        c = __builtin_amdgcn_mfma_f32_16x16x32_bf16(aagg1, bw[0][nt][1], c, 0, 0, 0);
        c = __builtin_amdgcn_mfma_f32_16x16x32_bf16(ax0,   bw[1][nt][0], c, 0, 0, 0);
        c = __builtin_amdgcn_mfma_f32_16x16x32_bf16(ax1,   bw[1][nt][1], c, 0, 0, 0);
        acc[nt] = c;
    }

    // ---- epilogue: relu, per-wave LDS transpose, coalesced stores ----
#pragma unroll
    for (int nt = 0; nt < 4; ++nt)
#pragma unroll
        for (int r = 0; r < 4; ++r)
            sOut[wv][quad * 4 + r][16 * nt + m] = fmaxf(acc[nt][r], 0.f);
#pragma unroll
    for (int p = 0; p < 4; ++p) {
        int idx = p * 64 + lane;          // 0..255
        int row = idx >> 4;               // 0..15
        int c4  = (idx & 15) * 4;         // 0..60
        float4 v = *(const float4*)&sOut[wv][row][c4];
        *(float4*)(out + (size_t)(node0 + row) * 64 + c4) = v;
    }
}

extern "C" void kernel_launch(void* const* d_in, const int* in_sizes, int n_in,
                              void* d_out, int out_size, void* d_ws, size_t ws_size,
                              hipStream_t stream)
{
    const float* x     = (const float*)d_in[0];
    const int*   eidx  = (const int*)d_in[1];
    const float* eattr = (const float*)d_in[2];
    const float* Wrel  = (const float*)d_in[3];
    const float* brel  = (const float*)d_in[4];
    const float* Wroot = (const float*)d_in[5];
    float* out = (float*)d_out;

    const int* src = eidx;
    const int* dst = eidx + N_EDGES;

    // Workspace (~40 MB of 256 MiB): gcur (pad 1024 ints) | bucketed 14 MB |
    // xb 12.8 MB | wb 16 KB | aggb 12.8 MB. No aliasing: bucketed AND xb
    // are both live during scatter_kernel.
    int*      gcur     = (int*)d_ws;
    int2*     bucketed = (int2*)(gcur + 1024);
    ushort*   xb       = (ushort*)(bucketed + (size_t)NB * CAP_B);
    ushort*   wb       = xb + (size_t)N_NODES * D;
    ushort*   aggb     = wb + 2 * D * D;

    hipMemsetAsync(gcur, 0, NB * sizeof(int), stream);

    bin_kernel<<<NBIN_BLOCKS, 256, 0, stream>>>(src, dst, eattr, gcur, bucketed);
    convert_kernel<<<(N_NODES * D / 4 + 255) / 256, 256, 0, stream>>>(x, xb);
    wprep_kernel<<<(2 * D * D + 255) / 256, 256, 0, stream>>>(Wrel, Wroot, wb);
    scatter_kernel<<<NB, 1024, 0, stream>>>(gcur, bucketed, xb, aggb);
    linear_kernel<<<(N_NODES + 63) / 64, 256, 0, stream>>>(xb, aggb, out, wb, brel);
}

// Round 5
// 183.154 us; speedup vs baseline: 4.5755x; 4.5303x over previous
//
#include <hip/hip_runtime.h>
#include <hip/hip_bf16.h>

#define N_NODES 100000
#define N_EDGES 1600000
#define D 64
#define SLOT 48               // padded slots per node
#define WSCALE 32767.0f

#define BSHIFT 9
#define BNODES 512                                  // nodes per bucket
#define NB 196                                      // ceil(100000/512)
#define CAP_B 8960                                  // mean 8192, sd ~90 -> 8.5 sigma
#define CHUNK 4096
#define NBIN_BLOCKS ((N_EDGES + CHUNK - 1) / CHUNK) // 391

__device__ inline ushort f2bu(float f) {
    __hip_bfloat16 h = __float2bfloat16(f);
    return *(ushort*)&h;
}

// ---------------------------------------------------------------------------
// 1. Bin edges by dst bucket. (byte-identical — known good)
// ---------------------------------------------------------------------------
__global__ __launch_bounds__(256) void bin_kernel(
    const int* __restrict__ src,
    const int* __restrict__ dst,
    const float* __restrict__ w,
    int* __restrict__ gcur,
    int2* __restrict__ bucketed)
{
    __shared__ int h[NB];
    __shared__ int cur[NB];
    __shared__ int sdst[CHUNK];      // 16 KB
    int tid = threadIdx.x;
    for (int b = tid; b < NB; b += 256) h[b] = 0;
    __syncthreads();

    int e0 = blockIdx.x * CHUNK;
    for (int i = tid; i < CHUNK; i += 256) {
        int e = e0 + i;
        int d = (e < N_EDGES) ? dst[e] : -1;
        sdst[i] = d;
        if (d >= 0) atomicAdd(&h[d >> BSHIFT], 1);
    }
    __syncthreads();

    for (int b = tid; b < NB; b += 256) {
        int c = h[b];
        cur[b] = (c > 0) ? atomicAdd(&gcur[b], c) : 0;
    }
    __syncthreads();

    for (int i = tid; i < CHUNK; i += 256) {
        int e = e0 + i;
        int d = sdst[i];
        if (d >= 0) {
            int b = d >> BSHIFT;
            int p = atomicAdd(&cur[b], 1);
            int q = (int)(w[e] * WSCALE + 0.5f);
            q = min(q, 32767);
            unsigned pk = (unsigned)src[e] | ((unsigned)q << 17);
            if (p < CAP_B)
                bucketed[(size_t)b * CAP_B + p] = make_int2((int)pk, d & (BNODES - 1));
        }
    }
}

// ---------------------------------------------------------------------------
// 2. Per-bucket fine fill — REWRITTEN: build the 512x48 slot image in LDS
//    (96 KB) and write it out with coalesced uint4 streams. Replaces the
//    1.6M fully-scattered 4-B global stores (64 L2 transactions per wave
//    instr) with 18.8 MB of sequential dwordx4 stores (~3 us at BW).
//    Semantics identical: same atomicAdd slot positions, same SLOT
//    truncation; rows' garbage beyond cnt is never read by gather.
// ---------------------------------------------------------------------------
#define FILL_T 512

__global__ __launch_bounds__(FILL_T) void bucket_fill_kernel(
    const int* __restrict__ gcur,
    const int2* __restrict__ bucketed,
    int* __restrict__ cnt,
    unsigned* __restrict__ slots)
{
    __shared__ int lcnt[BNODES];                         // 2 KB
    __shared__ unsigned __align__(16) img[BNODES * SLOT]; // 96 KB
    int tid = threadIdx.x;
    int b = blockIdx.x;
    for (int i = tid; i < BNODES; i += FILL_T) lcnt[i] = 0;
    __syncthreads();

    int nE = min(gcur[b], CAP_B);
    const int2* be = bucketed + (size_t)b * CAP_B;
    for (int i = tid; i < nE; i += FILL_T) {
        int2 v = be[i];
        int dl = v.y;
        int p = atomicAdd(&lcnt[dl], 1);
        if (p < SLOT)
            img[dl * SLOT + p] = (unsigned)v.x;          // LDS scatter (cheap)
    }
    __syncthreads();

    const size_t base = (size_t)b * BNODES * SLOT;
#pragma unroll
    for (int k = 0; k < (BNODES * SLOT / 4) / FILL_T; ++k) {
        int i = k * FILL_T + tid;                        // 6144 uint4s
        *(uint4*)(slots + base + 4 * (size_t)i) = *(const uint4*)&img[4 * i];
    }
    for (int i = tid; i < BNODES; i += FILL_T)
        cnt[b * BNODES + i] = min(lcnt[i], SLOT);
}

// ---------------------------------------------------------------------------
// 3a. Convert x -> bf16 (xb). (byte-identical to round 2)
// ---------------------------------------------------------------------------
__global__ __launch_bounds__(256) void convert_kernel(
    const float* __restrict__ x,
    ushort* __restrict__ xb)
{
    int i = (blockIdx.x * 256 + threadIdx.x) * 4;
    if (i >= N_NODES * D) return;
    float4 v = *(const float4*)(x + i);
    ushort4 o;
    o.x = f2bu(v.x); o.y = f2bu(v.y); o.z = f2bu(v.z); o.w = f2bu(v.w);
    *(ushort4*)(xb + i) = o;
}

// ---------------------------------------------------------------------------
// 3b. Convert Wrel|Wroot -> bf16 once. (byte-identical to round 2)
// ---------------------------------------------------------------------------
__global__ __launch_bounds__(256) void wprep_kernel(
    const float* __restrict__ Wrel,
    const float* __restrict__ Wroot,
    ushort* __restrict__ wb)
{
    int i = blockIdx.x * 256 + threadIdx.x;   // 0..8191
    if (i >= 2 * D * D) return;
    float f = (i < D * D) ? Wrel[i] : Wroot[i - D * D];
    wb[i] = f2bu(f);
}

// ---------------------------------------------------------------------------
// 4. Gather: one 8-lane group per node, 32 nodes/block. (byte-identical to
//    round 2 — verified 195 us pipeline)
// ---------------------------------------------------------------------------
__global__ __launch_bounds__(256) void gather_kernel(
    const ushort* __restrict__ xb,
    const int* __restrict__ cnt,
    const unsigned* __restrict__ slots,
    ushort* __restrict__ aggb)
{
    int tid  = threadIdx.x;
    int node = blockIdx.x * 32 + (tid >> 3);   // exact: 3125*32 = 100000
    int t    = tid & 7;                        // feature oct 0..7

    int dg = min(cnt[node], SLOT);
    const unsigned* __restrict__ row = slots + (size_t)node * SLOT;

    float a0 = 0.f, a1 = 0.f, a2 = 0.f, a3 = 0.f;
    float a4 = 0.f, a5 = 0.f, a6 = 0.f, a7 = 0.f;
#pragma unroll 2
    for (int j = 0; j < dg; ++j) {
        unsigned v = row[j];                   // 8 lanes, same addr: broadcast
        int s = v & 0x1FFFF;
        float wv = (float)(v >> 17) * (1.0f / WSCALE);
        uint4 dx = *(const uint4*)(xb + (size_t)s * D + 8 * t);
        a0 += __uint_as_float(dx.x << 16)         * wv;
        a1 += __uint_as_float(dx.x & 0xFFFF0000u) * wv;
        a2 += __uint_as_float(dx.y << 16)         * wv;
        a3 += __uint_as_float(dx.y & 0xFFFF0000u) * wv;
        a4 += __uint_as_float(dx.z << 16)         * wv;
        a5 += __uint_as_float(dx.z & 0xFFFF0000u) * wv;
        a6 += __uint_as_float(dx.w << 16)         * wv;
        a7 += __uint_as_float(dx.w & 0xFFFF0000u) * wv;
    }

    union { ushort u[8]; uint4 q; } pk;
    pk.u[0] = f2bu(a0); pk.u[1] = f2bu(a1);
    pk.u[2] = f2bu(a2); pk.u[3] = f2bu(a3);
    pk.u[4] = f2bu(a4); pk.u[5] = f2bu(a5);
    pk.u[6] = f2bu(a6); pk.u[7] = f2bu(a7);
    *(uint4*)(aggb + (size_t)node * D + 8 * t) = pk.q;   // 16 B, coalesced
}

// ---------------------------------------------------------------------------
// 5. Linear via bf16 MFMA (16x16x32). (byte-identical to round 2)
// ---------------------------------------------------------------------------
typedef __attribute__((ext_vector_type(8))) short bf8;
typedef __attribute__((ext_vector_type(4))) float f4;

__global__ __launch_bounds__(256) void linear_kernel(
    const ushort* __restrict__ xb,
    const ushort* __restrict__ aggb,
    float* __restrict__ out,
    const ushort* __restrict__ wb,    // [2][64][64] bf16: Wrel | Wroot
    const float* __restrict__ brel)
{
    __shared__ float __align__(16) sOut[4][16][68];   // 17.4 KB, per-wave use

    int tid  = threadIdx.x;
    int wv   = tid >> 6, lane = tid & 63;
    int node0 = (blockIdx.x * 4 + wv) * 16;
    if (node0 >= N_NODES) return;     // wave-uniform; no barriers below

    int m    = lane & 15;             // node-in-tile (A) / out-col (B, C/D)
    int quad = lane >> 4;             // 0..3

    // ---- B fragments: direct bf16 loads ----
    bf8 bw[2][4][2];                  // [mat][ntile][kstep]
#pragma unroll
    for (int mat = 0; mat < 2; ++mat)
#pragma unroll
        for (int nt = 0; nt < 4; ++nt)
#pragma unroll
            for (int s = 0; s < 2; ++s)
                bw[mat][nt][s] = *(const bf8*)(wb + mat * D * D
                                               + (16 * nt + m) * 64 + s * 32 + quad * 8);

    // ---- A fragments: agg (native bf16) and x (native bf16) ----
    const ushort* ar = aggb + (size_t)(node0 + m) * 64 + quad * 8;
    bf8 aagg0 = *(const bf8*)ar;
    bf8 aagg1 = *(const bf8*)(ar + 32);
    const ushort* xr = xb + (size_t)(node0 + m) * 64 + quad * 8;
    bf8 ax0 = *(const bf8*)xr;
    bf8 ax1 = *(const bf8*)(xr + 32);

    // ---- 16 MFMAs: 4 ntiles x (2 Ksteps x 2 matrices), bias in C-init ----
    f4 acc[4];
#pragma unroll
    for (int nt = 0; nt < 4; ++nt) {
        float b = brel[16 * nt + m];
        f4 c = {b, b, b, b};
        c = __builtin_amdgcn_mfma_f32_16x16x32_bf16(aagg0, bw[0][nt][0], c, 0, 0, 0);
        c = __builtin_amdgcn_mfma_f32_16x16x32_bf16(aagg1, bw[0][nt][1], c, 0, 0, 0);
        c = __builtin_amdgcn_mfma_f32_16x16x32_bf16(ax0,   bw[1][nt][0], c, 0, 0, 0);
        c = __builtin_amdgcn_mfma_f32_16x16x32_bf16(ax1,   bw[1][nt][1], c, 0, 0, 0);
        acc[nt] = c;
    }

    // ---- epilogue: relu, per-wave LDS transpose, coalesced stores ----
#pragma unroll
    for (int nt = 0; nt < 4; ++nt)
#pragma unroll
        for (int r = 0; r < 4; ++r)
            sOut[wv][quad * 4 + r][16 * nt + m] = fmaxf(acc[nt][r], 0.f);
#pragma unroll
    for (int p = 0; p < 4; ++p) {
        int idx = p * 64 + lane;          // 0..255
        int row = idx >> 4;               // 0..15
        int c4  = (idx & 15) * 4;         // 0..60
        float4 v = *(const float4*)&sOut[wv][row][c4];
        *(float4*)(out + (size_t)(node0 + row) * 64 + c4) = v;
    }
}

extern "C" void kernel_launch(void* const* d_in, const int* in_sizes, int n_in,
                              void* d_out, int out_size, void* d_ws, size_t ws_size,
                              hipStream_t stream)
{
    const float* x     = (const float*)d_in[0];
    const int*   eidx  = (const int*)d_in[1];
    const float* eattr = (const float*)d_in[2];
    const float* Wrel  = (const float*)d_in[3];
    const float* brel  = (const float*)d_in[4];
    const float* Wroot = (const float*)d_in[5];
    float* out = (float*)d_out;

    const int* src = eidx;
    const int* dst = eidx + N_EDGES;

    // Workspace (~46.6 MB of the 256 MiB ws): gcur (pad 1024 ints) | cnt |
    // bucketed | slots | wb (16 KB bf16 weights) | aggb (12.8 MB bf16 agg).
    // xb ALIASES bucketed (dead after bucket_fill; convert runs after fill).
    int*      gcur     = (int*)d_ws;
    int*      cnt      = gcur + 1024;
    int2*     bucketed = (int2*)(cnt + NB * BNODES);
    unsigned* slots    = (unsigned*)(bucketed + (size_t)NB * CAP_B);
    ushort*   wb       = (ushort*)(slots + (size_t)NB * BNODES * SLOT);
    ushort*   aggb     = wb + 2 * D * D;
    ushort*   xb       = (ushort*)bucketed;

    hipMemsetAsync(gcur, 0, NB * sizeof(int), stream);

    bin_kernel<<<NBIN_BLOCKS, 256, 0, stream>>>(src, dst, eattr, gcur, bucketed);
    bucket_fill_kernel<<<NB, FILL_T, 0, stream>>>(gcur, bucketed, cnt, slots);
    convert_kernel<<<(N_NODES * D / 4 + 255) / 256, 256, 0, stream>>>(x, xb);
    wprep_kernel<<<(2 * D * D + 255) / 256, 256, 0, stream>>>(Wrel, Wroot, wb);
    gather_kernel<<<N_NODES / 32, 256, 0, stream>>>(xb, cnt, slots, aggb);
    linear_kernel<<<(N_NODES + 63) / 64, 256, 0, stream>>>(xb, aggb, out, wb, brel);
}